// Round 1
// baseline (126.751 us; speedup 1.0000x reference)
//
#include <hip/hip_runtime.h>

using bf16x8 = __attribute__((ext_vector_type(8))) short;
using f32x4  = __attribute__((ext_vector_type(4))) float;

#define NTREES 100
#define KDIM   128
#define TOTCOLS (NTREES * 32)          // 3200 padded cols (32 per tree, node 31 = zeros)
#define BM 64                          // rows per block
#define TC 4                           // trees per chunk
#define CHUNK_COLS (TC * 32)           // 128
#define NCHUNKS (NTREES / TC)          // 25
#define BSTRIDE 136                    // padded k-stride (elems) in LDS: 272 B -> bank rotate

__device__ __forceinline__ void split_bf16(float v, unsigned short& h, unsigned short& l) {
  unsigned u = __float_as_uint(v);
  unsigned r = u + 0x7FFFu + ((u >> 16) & 1u);          // RNE to bf16
  unsigned short hu = (unsigned short)(r >> 16);
  float hf = __uint_as_float((unsigned)hu << 16);
  float res = v - hf;
  unsigned u2 = __float_as_uint(res);
  unsigned r2 = u2 + 0x7FFFu + ((u2 >> 16) & 1u);
  h = hu;
  l = (unsigned short)(r2 >> 16);
}

// kernel[T][F][31] f32  ->  col-major [col = t*32+n][k = f] bf16 hi/lo, scaled by 100 (1/tau)
__global__ void prep_b(const float* __restrict__ kern,
                       unsigned short* __restrict__ bhi,
                       unsigned short* __restrict__ blo) {
  __shared__ float kt[128][33];
  const int t = blockIdx.x;
  const int tid = threadIdx.x;
  const float* src = kern + (size_t)t * (128 * 31);
  for (int i = tid; i < 128 * 31; i += 128) {
    int f = i / 31, n = i - f * 31;
    kt[f][n] = src[i] * 100.0f;
  }
  __syncthreads();
  for (int n = 0; n < 32; ++n) {
    float v = (n < 31) ? kt[tid][n] : 0.0f;
    unsigned short h, l;
    split_bf16(v, h, l);
    size_t o = (size_t)(t * 32 + n) * KDIM + tid;
    bhi[o] = h;
    blo[o] = l;
  }
}

__global__ __launch_bounds__(256, 2) void gbm_main(
    const float* __restrict__ x,
    const unsigned short* __restrict__ bhi,
    const unsigned short* __restrict__ blo,
    const float* __restrict__ bias,
    const float* __restrict__ leaf,
    float* __restrict__ out)
{
  // LDS: B chunk (hi+lo, padded) = 2*128*136*2 = 69632 B; h tile (64x129 f32 = 33024 B)
  // and the final reduction buffer overlay the same region.
  __shared__ __align__(16) unsigned char lds_raw[2 * CHUNK_COLS * BSTRIDE * 2];
  unsigned short* bl_hi = (unsigned short*)lds_raw;
  unsigned short* bl_lo = bl_hi + CHUNK_COLS * BSTRIDE;
  float* hlds = (float*)lds_raw;
  float* red  = (float*)lds_raw;

  const int tid  = threadIdx.x;
  const int lane = tid & 63;
  const int w    = tid >> 6;                 // wave id = tree slot in chunk
  const int rowbase = blockIdx.x * BM;

  // ---- load x rows once, split to persistent A fragments (16x16x32 layout:
  //      row = lane&15, k = (lane>>4)*8 + j, j contiguous) ----
  bf16x8 a_hi[4][4], a_lo[4][4];
  {
    const int r0 = rowbase + (lane & 15);
    const int kb = (lane >> 4) * 8;
    #pragma unroll
    for (int rt = 0; rt < 4; ++rt) {
      const float* px = x + (size_t)(r0 + rt * 16) * KDIM + kb;
      #pragma unroll
      for (int ks = 0; ks < 4; ++ks) {
        float4 v0 = *(const float4*)(px + ks * 32);
        float4 v1 = *(const float4*)(px + ks * 32 + 4);
        float vals[8] = {v0.x, v0.y, v0.z, v0.w, v1.x, v1.y, v1.z, v1.w};
        bf16x8 h8, l8;
        #pragma unroll
        for (int j = 0; j < 8; ++j) {
          unsigned short hu, lu;
          split_bf16(vals[j], hu, lu);
          h8[j] = (short)hu;
          l8[j] = (short)lu;
        }
        a_hi[rt][ks] = h8;
        a_lo[rt][ks] = l8;
      }
    }
  }

  float outAcc = 0.0f;
  const int prow = tid & 63;     // postproc row
  const int pts  = tid >> 6;     // postproc tree slot

  for (int c = 0; c < NCHUNKS; ++c) {
    __syncthreads();             // previous postproc done before LDS overwrite

    // ---- stage B chunk (coalesced 16B loads -> padded col-major LDS) ----
    #pragma unroll
    for (int s = 0; s < 2; ++s) {
      const unsigned short* src = (s ? blo : bhi) + (size_t)c * CHUNK_COLS * KDIM;
      unsigned short* dst = s ? bl_lo : bl_hi;
      #pragma unroll
      for (int i = 0; i < 8; ++i) {
        int t16 = tid + i * 256;             // 0..2047 16B-chunks
        int col = t16 >> 4;
        int kk  = (t16 & 15) * 8;
        int4 v = *(const int4*)(src + t16 * 8);
        *(int4*)(dst + col * BSTRIDE + kk) = v;
      }
    }
    __syncthreads();

    // ---- MFMA: 3-pass bf16 split GEMM, this wave's tree (cols w*32..w*32+31) ----
    f32x4 acc[4][2] = {};
    {
      const int bcol = w * 32 + (lane & 15);
      const int kb   = (lane >> 4) * 8;
      #pragma unroll
      for (int ks = 0; ks < 4; ++ks) {
        const int ko = ks * 32 + kb;
        bf16x8 bh0 = *(const bf16x8*)(bl_hi + (size_t)(bcol)      * BSTRIDE + ko);
        bf16x8 bh1 = *(const bf16x8*)(bl_hi + (size_t)(bcol + 16) * BSTRIDE + ko);
        bf16x8 bL0 = *(const bf16x8*)(bl_lo + (size_t)(bcol)      * BSTRIDE + ko);
        bf16x8 bL1 = *(const bf16x8*)(bl_lo + (size_t)(bcol + 16) * BSTRIDE + ko);
        #pragma unroll
        for (int rt = 0; rt < 4; ++rt) {
          acc[rt][0] = __builtin_amdgcn_mfma_f32_16x16x32_bf16(a_hi[rt][ks], bh0, acc[rt][0], 0, 0, 0);
          acc[rt][0] = __builtin_amdgcn_mfma_f32_16x16x32_bf16(a_lo[rt][ks], bh0, acc[rt][0], 0, 0, 0);
          acc[rt][0] = __builtin_amdgcn_mfma_f32_16x16x32_bf16(a_hi[rt][ks], bL0, acc[rt][0], 0, 0, 0);
          acc[rt][1] = __builtin_amdgcn_mfma_f32_16x16x32_bf16(a_hi[rt][ks], bh1, acc[rt][1], 0, 0, 0);
          acc[rt][1] = __builtin_amdgcn_mfma_f32_16x16x32_bf16(a_lo[rt][ks], bh1, acc[rt][1], 0, 0, 0);
          acc[rt][1] = __builtin_amdgcn_mfma_f32_16x16x32_bf16(a_hi[rt][ks], bL1, acc[rt][1], 0, 0, 0);
        }
      }
    }
    __syncthreads();             // all waves done reading B before overlaying h

    // ---- scatter h (D layout: col=lane&15, row=(lane>>4)*4+reg) to LDS ----
    {
      const int hr = (lane >> 4) * 4;
      const int hc = lane & 15;
      #pragma unroll
      for (int rt = 0; rt < 4; ++rt)
        #pragma unroll
        for (int ct = 0; ct < 2; ++ct)
          #pragma unroll
          for (int r = 0; r < 4; ++r)
            hlds[(size_t)(rt * 16 + hr + r) * 129 + w * 32 + ct * 16 + hc] = acc[rt][ct][r];
    }
    __syncthreads();

    // ---- tree eval: probs = prod of sigmoids down the path, dot with leaf ----
    {
      const int tree = c * TC + pts;
      const float* hrow = hlds + (size_t)prow * 129 + pts * 32;
      const float* bp = bias + (size_t)tree * 31;
      const float* lp = leaf + (size_t)tree * 32;
      float cum[32];
      cum[0] = 1.0f;
      #pragma unroll
      for (int d = 0; d < 5; ++d) {
        #pragma unroll
        for (int i = (1 << d) - 1; i >= 0; --i) {
          const int node = (1 << d) - 1 + i;
          float z = fmaf(bp[node], 100.0f, hrow[node]);   // (h + b)/tau
          z = fminf(32.0f, fmaxf(-32.0f, z));             // reference clip
          float e  = __expf(-z);
          float sl = __builtin_amdgcn_rcpf(1.0f + e);     // sigma(z)  -> left
          float sr = e * sl;                              // sigma(-z) -> right
          float cl = cum[i];
          cum[2 * i]     = cl * sl;
          cum[2 * i + 1] = cl * sr;
        }
      }
      float s = 0.0f;
      #pragma unroll
      for (int l = 0; l < 32; ++l)
        s = fmaf(cum[l], lp[l], s);
      outAcc += s;
    }
  }

  // ---- reduce the 4 tree-slot partials per row, write out ----
  __syncthreads();
  red[tid] = outAcc;
  __syncthreads();
  if (tid < 64)
    out[rowbase + tid] = red[tid] + red[tid + 64] + red[tid + 128] + red[tid + 192];
}

extern "C" void kernel_launch(void* const* d_in, const int* in_sizes, int n_in,
                              void* d_out, int out_size, void* d_ws, size_t ws_size,
                              hipStream_t stream) {
  const float* x    = (const float*)d_in[0];
  const float* kern = (const float*)d_in[1];
  const float* bias = (const float*)d_in[2];
  const float* leaf = (const float*)d_in[3];
  // d_in[4] = route: topology is hard-coded (perfect depth-5 tree, bit0=left)

  unsigned short* bhi = (unsigned short*)d_ws;
  unsigned short* blo = bhi + (size_t)TOTCOLS * KDIM;   // 819200 B each

  prep_b<<<NTREES, 128, 0, stream>>>(kern, bhi, blo);
  gbm_main<<<32768 / BM, 256, 0, stream>>>(x, bhi, blo, bias, leaf, (float*)d_out);
}